// Round 4
// baseline (172.208 us; speedup 1.0000x reference)
//
#include <hip/hip_runtime.h>

// Ordered bi-bi mechanism dydt. Species: [E, EA, EQ, EAB, A, B, P, Q].
// Layout: lane pair (2j, 2j+1) holds the two float4 halves of element j, so
// every global access is unit-stride float4 across the wave. Halves + rates
// exchanged via __shfl_xor(.,1). Two rows per thread for memory-level
// parallelism. Output uses NON-TEMPORAL stores: round-2 counters showed
// FETCH_SIZE == output size exactly -> store-miss write-allocate was reading
// 64 MB of doomed lines from HBM. nt stores skip the allocate.
// (__builtin_nontemporal_store needs a native clang vector type, not HIP's
// float4 wrapper class -> use ext_vector_type(4).)

typedef float nfloat4 __attribute__((ext_vector_type(4)));

__device__ __forceinline__ nfloat4 process_row(float4 q, float4 mine, int h) {
    // q   = this lane's y half; mine = kf row (even lane) / kr row (odd lane)
    float4 p;
    p.x = __shfl_xor(q.x, 1);
    p.y = __shfl_xor(q.y, 1);
    p.z = __shfl_xor(q.z, 1);
    p.w = __shfl_xor(q.w, 1);

    float4 ya = h ? p : q;   // E, EA, EQ, EAB
    float4 yb = h ? q : p;   // A, B, P, Q

    float4 other;
    other.x = __shfl_xor(mine.x, 1);
    other.y = __shfl_xor(mine.y, 1);
    other.z = __shfl_xor(mine.z, 1);
    other.w = __shfl_xor(mine.w, 1);

    float4 f = h ? other : mine;   // kf0..kf3
    float4 r = h ? mine : other;   // kr0..kr3

    float E  = ya.x, EA = ya.y, EQ = ya.z, EAB = ya.w;
    float A  = yb.x, Bc = yb.y, P  = yb.z, Q   = yb.w;

    float v0 = f.x * E   * A  - r.x * EA;
    float v1 = f.y * EA  * Bc - r.y * EAB;
    float v2 = f.z * EAB      - r.z * EQ * P;
    float v3 = f.w * EQ       - r.w * E  * Q;

    nfloat4 o;
    if (h == 0) {
        o.x = v3 - v0;   // dE
        o.y = v0 - v1;   // dEA
        o.z = v2 - v3;   // dEQ
        o.w = v1 - v2;   // dEAB
    } else {
        o.x = -v0;       // dA
        o.y = -v1;       // dB
        o.z =  v2;       // dP
        o.w =  v3;       // dQ
    }
    return o;
}

__global__ __launch_bounds__(256) void ode_kernel(
    const float4* __restrict__ y4,
    const float4* __restrict__ kf4,
    const float4* __restrict__ kr4,
    nfloat4* __restrict__ out4,
    int n2)   // n2 = 2*B float4 rows
{
    const int tid = threadIdx.x;
    const int r0 = blockIdx.x * 512 + tid;
    const int r1 = r0 + 256;

    if (r0 < n2) {
        // issue all independent loads up front (compiler schedules them together)
        float4 q0 = y4[r0];
        float4 m0 = ((r0 & 1) ? kr4 : kf4)[r0 >> 1];
        if (r1 < n2) {
            float4 q1 = y4[r1];
            float4 m1 = ((r1 & 1) ? kr4 : kf4)[r1 >> 1];
            nfloat4 o0 = process_row(q0, m0, r0 & 1);
            nfloat4 o1 = process_row(q1, m1, r1 & 1);
            __builtin_nontemporal_store(o0, &out4[r0]);
            __builtin_nontemporal_store(o1, &out4[r1]);
        } else {
            nfloat4 o0 = process_row(q0, m0, r0 & 1);
            __builtin_nontemporal_store(o0, &out4[r0]);
        }
    }
}

extern "C" void kernel_launch(void* const* d_in, const int* in_sizes, int n_in,
                              void* d_out, int out_size, void* d_ws, size_t ws_size,
                              hipStream_t stream) {
    // inputs: [0]=t (1,), [1]=y (B,8), [2]=forward_rates (B,4), [3]=reverse_rates (B,4)
    const float4* y4  = (const float4*)d_in[1];
    const float4* kf4 = (const float4*)d_in[2];
    const float4* kr4 = (const float4*)d_in[3];
    nfloat4* out4 = (nfloat4*)d_out;
    int B  = in_sizes[1] / 8;
    int n2 = 2 * B;

    int block = 256;
    int rows_per_block = block * 2;
    int grid = (n2 + rows_per_block - 1) / rows_per_block;
    ode_kernel<<<grid, block, 0, stream>>>(y4, kf4, kr4, out4, n2);
}